// Round 6
// baseline (307.252 us; speedup 1.0000x reference)
//
#include <hip/hip_runtime.h>
#include <math.h>

#define NB   8
#define NCC  16384
#define HID  128

typedef __attribute__((ext_vector_type(8))) short short8;
typedef __attribute__((ext_vector_type(4))) float f32x4;

#define MFMA(a,b,c) __builtin_amdgcn_mfma_f32_16x16x32_bf16(a,b,c,0,0,0)

// ---- ws float offsets ----
#define WS_AABS   0
#define WS_BASE1  8
#define WS_BOUT   2056
#define WS_BSUMR  2120
#define WS_BSUMZ  2248
#define WS_BIHN   2376
#define WS_BHHN   2504
#define WS_W64    2632
#define WS_STAT   3016
#define WS_INTERF 3024
#define WS_FRAG   3152        // 61440 floats = 122880 bf16 frags
#define WS_SD     64592      // 64*128
#define WS_HM     72784      // 1024
#define WS_AVGT   73808      // 16384  (unique writer per chunk, plain stores)
#define WS_FMEAN  90192      // 64*128
#define WS_GLOB   98384      // 8*128
#define WS_PART2  99408      // 256*64
#define WS_FPART  115792     // 8*1024*128 (unique writer per (b,chunk))
#define WS_CO     1164368    // 16384*64   (unique writer per chunk)
// end = 2212944 floats = 8.85 MB

// frag sub-offsets in shorts
#define FO_W1  0
#define FO_W2  32768
#define FO_WIH 49152
#define FO_WHH 73728

__device__ __forceinline__ unsigned short f2b(float f) {
    unsigned int u = __float_as_uint(f);
    unsigned int r = (u + 0x7fffu + ((u >> 16) & 1u)) >> 16;
    return (unsigned short)r;
}
__device__ __forceinline__ float b2f(unsigned short us) {
    return __uint_as_float(((unsigned int)us) << 16);
}
__device__ __forceinline__ float sigm(float x) {
    return __builtin_amdgcn_rcpf(1.f + __expf(-x));
}
__device__ __forceinline__ float tanh_fast(float x) {
    return 1.f - 2.f * __builtin_amdgcn_rcpf(__expf(2.f * x) + 1.f);
}
__device__ __forceinline__ void stg(char* dst, int row, int cb, float4 u, float4 v) {
    unsigned int p0 = (unsigned)f2b(u.x) | ((unsigned)f2b(u.y) << 16);
    unsigned int p1 = (unsigned)f2b(u.z) | ((unsigned)f2b(u.w) << 16);
    unsigned int p2 = (unsigned)f2b(v.x) | ((unsigned)f2b(v.y) << 16);
    unsigned int p3 = (unsigned)f2b(v.z) | ((unsigned)f2b(v.w) << 16);
    uint4 pk = make_uint4(p0, p1, p2, p3);
    *(uint4*)(dst + row * 256 + (cb ^ ((row & 7) << 4))) = pk;
}

// ---------------- small prep ----------------
__global__ __launch_bounds__(256) void k0s(
    const float* __restrict__ x, const float* __restrict__ noise,
    const float* __restrict__ amps,
    const float* __restrict__ eaW1, const float* __restrict__ eaB1,
    const float* __restrict__ egW1, const float* __restrict__ egB1,
    const float* __restrict__ eaB2, const float* __restrict__ egB2,
    const float* __restrict__ gbih, const float* __restrict__ gbhh,
    const float* __restrict__ gWih, float* __restrict__ ws)
{
    __shared__ float xb[8][64];
    int t = threadIdx.x;
    for (int i = t; i < 512; i += 256) {
        int b = i >> 6, k = i & 63;
        xb[b][k] = x[k] + noise[b * 64 + k] * (0.05f * (float)(b + 1));
    }
    if (t == 0) {
        float s = 0.f;
        for (int b = 0; b < 8; b++) s += fabsf(amps[b]);
        s += 1e-8f;
        for (int b = 0; b < 8; b++) ws[WS_AABS + b] = fabsf(amps[b]) / s;
    }
    __syncthreads();
    for (int i = t; i < 2048; i += 256) {
        int b = i >> 8, n = i & 255;
        const float* Wp; float s;
        if (n < 128) { Wp = eaW1 + n * 192; s = eaB1[n]; }
        else         { Wp = egW1 + (n - 128) * 192; s = egB1[n - 128]; }
        for (int k = 0; k < 64; k++) s += xb[b][k] * Wp[k];
        ws[WS_BASE1 + i] = s;
    }
    if (t < 64) ws[WS_BOUT + t] = eaB2[t] - egB2[t];
    if (t < 128) {
        ws[WS_BSUMR + t] = gbih[t] + gbhh[t];
        ws[WS_BSUMZ + t] = gbih[128 + t] + gbhh[128 + t];
        ws[WS_BIHN + t]  = gbih[256 + t];
        ws[WS_BHHN + t]  = gbhh[256 + t];
    }
    for (int i = t; i < 384; i += 256) ws[WS_W64 + i] = gWih[i * 65 + 64];
}

// ---------------- weight -> MFMA B-fragment pre-swizzle ----------------
__global__ __launch_bounds__(1024) void kfrag(
    const float* __restrict__ eaW1, const float* __restrict__ egW1,
    const float* __restrict__ eaW2, const float* __restrict__ egW2,
    const float* __restrict__ gWih, const float* __restrict__ gWhh,
    float* __restrict__ ws)
{
    int i = blockIdx.x * 1024 + threadIdx.x;
    if (i >= 122880) return;
    short* wsh = (short*)(ws + WS_FRAG);
    float v;
    if (i < 32768) {                       // W1: K=128, N=256 (a|g), KT=4
        int rel = i;
        int j = rel & 7, l = (rel >> 3) & 63, tk = rel >> 9;
        int kt = tk & 3, nt = tk >> 2;
        int n = nt * 16 + (l & 15), k = kt * 32 + ((l >> 4) << 3) + j;
        v = (n < 128) ? eaW1[n * 192 + 64 + k] : egW1[(n - 128) * 192 + 64 + k];
    } else if (i < 49152) {                // W2: K=256 ([A1|G1]), N=64, KT=8
        int rel = i - 32768;
        int j = rel & 7, l = (rel >> 3) & 63, tk = rel >> 9;
        int kt = tk & 7, nt = tk >> 3;
        int d = nt * 16 + (l & 15), k = kt * 32 + ((l >> 4) << 3) + j;
        v = (k < 128) ? eaW2[d * 128 + k] : -egW2[d * 128 + (k - 128)];
    } else if (i < 73728) {                // WIH: K=64, N=384, KT=2
        int rel = i - 49152;
        int j = rel & 7, l = (rel >> 3) & 63, tk = rel >> 9;
        int kt = tk & 1, nt = tk >> 1;
        int r = nt * 16 + (l & 15), k = kt * 32 + ((l >> 4) << 3) + j;
        v = gWih[r * 65 + k];
    } else {                               // WHH: K=128, N=384, KT=4
        int rel = i - 73728;
        int j = rel & 7, l = (rel >> 3) & 63, tk = rel >> 9;
        int kt = tk & 3, nt = tk >> 2;
        int r = nt * 16 + (l & 15), k = kt * 32 + ((l >> 4) << 3) + j;
        v = gWhh[r * 128 + k];
    }
    wsh[i] = (short)f2b(v);
}

// ---------------- main MFMA kernel ----------------
// grid 1024 chunks x 16 cells; 256 threads (4 waves); 4 branch-PAIRS in-loop.
// Pair batching: each weight fragment loaded once, used for 2 MFMAs.
// No global atomics: all CO/FPART/AVGT destinations have unique writers.
__global__ __launch_bounds__(256, 4) void k1_cells(
    const float* __restrict__ hiddens, float* __restrict__ newh,
    float* __restrict__ ws)
{
    __shared__ char  hsb[2][2][16 * 256];  // [pairbuf][branch] bf16 [16][128] swizzled
    __shared__ char  agb[2][16 * 512];     // [branch] bf16 [16][256]
    __shared__ char  otb[2][16 * 128];     // [branch] bf16 [16][64]
    __shared__ float ts_s[2][16];
    __shared__ float tsum_s[16];

    const int t    = threadIdx.x;
    const int lane = t & 63;
    const int nq   = t >> 6;           // wave id = N-quarter
    const int col  = lane & 15;
    const int kq   = lane >> 4;        // 0..3
    const int chunk = blockIdx.x;
    const int n0   = chunk * 16;

    const short* wsh   = (const short*)(ws + WS_FRAG);
    const short8* W1F  = (const short8*)(wsh + FO_W1);
    const short8* W2F  = (const short8*)(wsh + FO_W2);
    const short8* WIHF = (const short8*)(wsh + FO_WIH);
    const short8* WHHF = (const short8*)(wsh + FO_WHH);

    float co_reg[4];
#pragma unroll
    for (int i = 0; i < 4; i++) co_reg[i] = 0.f;
    if (t < 16) tsum_s[t] = 0.f;

    const int flat = t * 8;            // 2048 floats per branch tile
    const int srow = t >> 4;           // 0..15
    const int scb  = (t & 15) * 16;    // byte col

    // prologue: stage pair 0 (branches 0,1), prefetch pair 1 (branches 2,3)
    {
        const float* h0 = hiddens + ((size_t)(0 * NCC + n0)) * HID;
        const float* h1 = hiddens + ((size_t)(1 * NCC + n0)) * HID;
        float4 a0 = *(const float4*)(h0 + flat);
        float4 a1 = *(const float4*)(h0 + flat + 4);
        float4 b0 = *(const float4*)(h1 + flat);
        float4 b1 = *(const float4*)(h1 + flat + 4);
        stg(hsb[0][0], srow, scb, a0, a1);
        stg(hsb[0][1], srow, scb, b0, b1);
    }
    const float* hp0 = hiddens + ((size_t)(2 * NCC + n0)) * HID;
    const float* hp1 = hiddens + ((size_t)(3 * NCC + n0)) * HID;
    float4 pfa0 = *(const float4*)(hp0 + flat);
    float4 pfa1 = *(const float4*)(hp0 + flat + 4);
    float4 pfb0 = *(const float4*)(hp1 + flat);
    float4 pfb1 = *(const float4*)(hp1 + flat + 4);
    __syncthreads();

    for (int p = 0; p < 4; ++p) {
        const int cur = p & 1;
        const int b = 2 * p;
        const char* h0 = hsb[cur][0];
        const char* h1 = hsb[cur][1];
        if (t < 32) ((float*)ts_s)[t] = 0.f;

        // ---- L1: relu(H @ W1^T + base1), 16x256, K=128, both branches ----
        {
            short8 aH0[4], aH1[4];
#pragma unroll
            for (int ks = 0; ks < 4; ks++) {
                int off = (ks * 64 + (kq << 4)) ^ ((col & 7) << 4);
                aH0[ks] = *(const short8*)(h0 + col * 256 + off);
                aH1[ks] = *(const short8*)(h1 + col * 256 + off);
            }
#pragma unroll
            for (int nti = 0; nti < 4; nti++) {
                int nt = nq * 4 + nti;
                f32x4 ac0 = {0.f, 0.f, 0.f, 0.f};
                f32x4 ac1 = {0.f, 0.f, 0.f, 0.f};
#pragma unroll
                for (int kt = 0; kt < 4; kt++) {
                    short8 bf = W1F[(nt * 4 + kt) * 64 + lane];
                    ac0 = MFMA(aH0[kt], bf, ac0);
                    ac1 = MFMA(aH1[kt], bf, ac1);
                }
                int n = nt * 16 + col;
                float bs0 = ws[WS_BASE1 + b * 256 + n];
                float bs1 = ws[WS_BASE1 + (b + 1) * 256 + n];
#pragma unroll
                for (int j = 0; j < 4; j++) {
                    int row = (kq << 2) + j;
                    int off = ((n * 2) ^ ((row & 7) << 4));
                    *(unsigned short*)(agb[0] + row * 512 + off) = f2b(fmaxf(ac0[j] + bs0, 0.f));
                    *(unsigned short*)(agb[1] + row * 512 + off) = f2b(fmaxf(ac1[j] + bs1, 0.f));
                }
            }
        }
        __syncthreads();  // A: agb ready

        // ---- L2: out = [A1|G1] @ [W2A;-W2G] + bout, 16x64, K=256 ----
        {
            f32x4 oc0 = {0.f, 0.f, 0.f, 0.f};
            f32x4 oc1 = {0.f, 0.f, 0.f, 0.f};
#pragma unroll
            for (int kt = 0; kt < 8; kt++) {
                int off = (kt * 64 + (kq << 4)) ^ ((col & 7) << 4);
                short8 a0 = *(const short8*)(agb[0] + col * 512 + off);
                short8 a1 = *(const short8*)(agb[1] + col * 512 + off);
                short8 bf = W2F[(nq * 8 + kt) * 64 + lane];
                oc0 = MFMA(a0, bf, oc0);
                oc1 = MFMA(a1, bf, oc1);
            }
            int d = nq * 16 + col;
            float bo = ws[WS_BOUT + d];
            float aab0 = ws[WS_AABS + b];
            float aab1 = ws[WS_AABS + b + 1];
#pragma unroll
            for (int j = 0; j < 4; j++) {
                int row = (kq << 2) + j;
                int off = ((d * 2) ^ ((row & 7) << 4));
                float v0 = oc0[j] + bo;
                float v1 = oc1[j] + bo;
                *(unsigned short*)(otb[0] + row * 128 + off) = f2b(v0);
                *(unsigned short*)(otb[1] + row * 128 + off) = f2b(v1);
                co_reg[j] += aab0 * v0 + aab1 * v1;
                float s0 = v0 * v0, s1 = v1 * v1;
                s0 += __shfl_xor(s0, 1); s1 += __shfl_xor(s1, 1);
                s0 += __shfl_xor(s0, 2); s1 += __shfl_xor(s1, 2);
                s0 += __shfl_xor(s0, 4); s1 += __shfl_xor(s1, 4);
                s0 += __shfl_xor(s0, 8); s1 += __shfl_xor(s1, 8);
                if (col == 0) {
                    atomicAdd(&ts_s[0][row], s0);
                    atomicAdd(&ts_s[1][row], s1);
                }
            }
        }
        __syncthreads();  // B: otb + ts_s ready

        if (p < 3) {
            stg(hsb[cur ^ 1][0], srow, scb, pfa0, pfa1);
            stg(hsb[cur ^ 1][1], srow, scb, pfb0, pfb1);
        }
        if (t < 16) tsum_s[t] += ts_s[0][t] + ts_s[1][t];

        // ---- GRU: gi (K=64 from out) + gh (K=128 from h), both branches ----
        {
#pragma unroll
            for (int hgi = 0; hgi < 2; hgi++) {
                int hg = nq * 2 + hgi;
                f32x4 R0 = {0.f,0.f,0.f,0.f}, R1 = {0.f,0.f,0.f,0.f};
                f32x4 Z0 = {0.f,0.f,0.f,0.f}, Z1 = {0.f,0.f,0.f,0.f};
                f32x4 I0 = {0.f,0.f,0.f,0.f}, I1 = {0.f,0.f,0.f,0.f};
                f32x4 N0 = {0.f,0.f,0.f,0.f}, N1 = {0.f,0.f,0.f,0.f};
#pragma unroll
                for (int ks = 0; ks < 2; ks++) {
                    int off = (ks * 64 + (kq << 4)) ^ ((col & 7) << 4);
                    short8 a0 = *(const short8*)(otb[0] + col * 128 + off);
                    short8 a1 = *(const short8*)(otb[1] + col * 128 + off);
                    short8 br = WIHF[(hg * 2 + ks) * 64 + lane];
                    short8 bz = WIHF[((hg + 8) * 2 + ks) * 64 + lane];
                    short8 bn = WIHF[((hg + 16) * 2 + ks) * 64 + lane];
                    R0 = MFMA(a0, br, R0); R1 = MFMA(a1, br, R1);
                    Z0 = MFMA(a0, bz, Z0); Z1 = MFMA(a1, bz, Z1);
                    I0 = MFMA(a0, bn, I0); I1 = MFMA(a1, bn, I1);
                }
#pragma unroll
                for (int ks = 0; ks < 4; ks++) {
                    int off = (ks * 64 + (kq << 4)) ^ ((col & 7) << 4);
                    short8 a0 = *(const short8*)(h0 + col * 256 + off);
                    short8 a1 = *(const short8*)(h1 + col * 256 + off);
                    short8 br = WHHF[(hg * 4 + ks) * 64 + lane];
                    short8 bz = WHHF[((hg + 8) * 4 + ks) * 64 + lane];
                    short8 bn = WHHF[((hg + 16) * 4 + ks) * 64 + lane];
                    R0 = MFMA(a0, br, R0); R1 = MFMA(a1, br, R1);
                    Z0 = MFMA(a0, bz, Z0); Z1 = MFMA(a1, bz, Z1);
                    N0 = MFMA(a0, bn, N0); N1 = MFMA(a1, bn, N1);
                }
                int h = hg * 16 + col;
                float bsr = ws[WS_BSUMR + h], bsz = ws[WS_BSUMZ + h];
                float bin = ws[WS_BIHN + h], bhn = ws[WS_BHHN + h];
                float wr = ws[WS_W64 + h], wz = ws[WS_W64 + 128 + h], wn = ws[WS_W64 + 256 + h];

                float fl0 = 0.f, fl1 = 0.f;
#pragma unroll
                for (int j = 0; j < 4; j++) {
                    int row = (kq << 2) + j;
                    int hoff = ((h * 2) ^ ((row & 7) << 4));
                    {
                        float tv = ts_s[0][row] * (1.f / 64.f);
                        float r  = sigm(R0[j] + bsr + tv * wr);
                        float z  = sigm(Z0[j] + bsz + tv * wz);
                        float nn = tanh_fast(I0[j] + bin + tv * wn + r * (N0[j] + bhn));
                        float hold = b2f(*(const unsigned short*)(h0 + row * 256 + hoff));
                        float nh = (1.f - z) * nn + z * hold;
                        newh[((size_t)(b * NCC + n0 + row)) * HID + h] = nh;
                        fl0 += nh;
                    }
                    {
                        float tv = ts_s[1][row] * (1.f / 64.f);
                        float r  = sigm(R1[j] + bsr + tv * wr);
                        float z  = sigm(Z1[j] + bsz + tv * wz);
                        float nn = tanh_fast(I1[j] + bin + tv * wn + r * (N1[j] + bhn));
                        float hold = b2f(*(const unsigned short*)(h1 + row * 256 + hoff));
                        float nh = (1.f - z) * nn + z * hold;
                        newh[((size_t)((b + 1) * NCC + n0 + row)) * HID + h] = nh;
                        fl1 += nh;
                    }
                }
                fl0 += __shfl_xor(fl0, 16); fl1 += __shfl_xor(fl1, 16);
                fl0 += __shfl_xor(fl0, 32); fl1 += __shfl_xor(fl1, 32);
                if (kq == 0) {
                    ws[WS_FPART + ((size_t)(b * 1024 + chunk)) * 128 + h] = fl0;
                    ws[WS_FPART + ((size_t)((b + 1) * 1024 + chunk)) * 128 + h] = fl1;
                }
            }
        }
        __syncthreads();  // C

        if (p < 2) {
            const float* q0 = hiddens + ((size_t)((b + 4) * NCC + n0)) * HID;
            const float* q1 = hiddens + ((size_t)((b + 5) * NCC + n0)) * HID;
            pfa0 = *(const float4*)(q0 + flat);
            pfa1 = *(const float4*)(q0 + flat + 4);
            pfb0 = *(const float4*)(q1 + flat);
            pfb1 = *(const float4*)(q1 + flat + 4);
        }
    }

    // ---- epilogue: plain stores (unique writers) ----
    {
        int d = nq * 16 + col;
#pragma unroll
        for (int j = 0; j < 4; j++) {
            int row = (kq << 2) + j;
            ws[WS_CO + (size_t)(n0 + row) * 64 + d] = co_reg[j];
        }
    }
    if (t < 16) ws[WS_AVGT + n0 + t] = tsum_s[t] * (1.f / 512.f);
}

// ---------------- faction means + debate-slice sums ----------------
__global__ __launch_bounds__(128) void k2_fmean(float* __restrict__ ws)
{
    int bf = blockIdx.x;               // 64 = 8 branches * 8 factions
    int b = bf >> 3, f = bf & 7;
    int h = threadIdx.x;
    float s = 0.f, s8 = 0.f;
    for (int j = 0; j < 128; j++) {    // 128 chunks of 16 cells per faction
        float v = ws[WS_FPART + ((size_t)(b * 1024 + f * 128 + j)) * 128 + h];
        s += v;
        if (j < 32) s8 += v;           // first 512 cells = debate slice
    }
    ws[WS_FMEAN + (b * 8 + f) * 128 + h] = s * (1.f / 2048.f);
    ws[WS_SD + (b * 8 + f) * 128 + h] = s8;
}

__global__ __launch_bounds__(1024) void k2_glob(float* __restrict__ ws)
{
    int t = threadIdx.x;
    int b = t >> 7, h = t & 127;
    float s = 0.f;
    for (int f = 0; f < 8; f++) s += ws[WS_FMEAN + (b * 8 + f) * 128 + h];
    ws[WS_GLOB + t] = s * 0.125f;
}

// ---------------- hm vector (post-blend branch means) ----------------
__global__ __launch_bounds__(1024) void k4hm(
    const int* __restrict__ step, float* __restrict__ ws)
{
    int t = threadIdx.x;
    int b = t >> 7, h = t & 127;
    float gl = ws[WS_GLOB + b * 128 + h];
    float tot = 16384.f * gl;
    if (step[0] > 5) {
        float sd = 0.f;
        for (int f = 0; f < 8; f++) sd += ws[WS_SD + (b * 8 + f) * 128 + h];
        float extra = 3481.6f * gl - 0.85f * sd;
        tot += 0.15f * extra;
    }
    ws[WS_HM + t] = tot * (1.f / 16384.f);
}

// ---------------- interference matvec ----------------
__global__ __launch_bounds__(256) void k4mv(
    const float* __restrict__ mixW, const float* __restrict__ mixb,
    float* __restrict__ ws)
{
    __shared__ float red[256];
    int h = blockIdx.x, t = threadIdx.x;
    float4 wv = *(const float4*)(mixW + (size_t)h * 1024 + t * 4);
    float4 hv = *(const float4*)(ws + WS_HM + t * 4);
    float s = wv.x * hv.x + wv.y * hv.y + wv.z * hv.z + wv.w * hv.w;
    red[t] = s; __syncthreads();
    for (int st = 128; st > 0; st >>= 1) { if (t < st) red[t] += red[t + st]; __syncthreads(); }
    if (t == 0) ws[WS_INTERF + h] = mixb[h] + red[0];
}

// ---------------- fused sync/debate blend + interf apply ----------------
__global__ __launch_bounds__(256) void k35_blend(
    float* __restrict__ newh, const float* __restrict__ ws,
    const int* __restrict__ step)
{
    int blk = blockIdx.x;              // 2048 = 8 * 256
    int b = blk >> 8, ck = blk & 255;
    int t = threadIdx.x;
    int h = t & 127, half = t >> 7;
    int base = ck * 64 + half * 32;
    int f = ck >> 5;
    bool deb = (step[0] > 5) && (((ck * 64) & 2047) < 512);
    float fm  = ws[WS_FMEAN + (b * 8 + f) * 128 + h];
    float gl  = ws[WS_GLOB + b * 128 + h];
    float itf = (b == 0) ? 0.05f * ws[WS_INTERF + h] : 0.f;
    for (int i = 0; i < 32; i++) {
        size_t idx = ((size_t)b * NCC + base + i) * HID + h;
        float v = newh[idx];
        v = 0.85f * v + 0.15f * fm;
        if (deb) v = 0.85f * v + 0.15f * gl;
        newh[idx] = v + itf;
    }
}

// ---------------- avg_t stats (max, denom, mean) ----------------
__global__ __launch_bounds__(1024) void kstat(float* __restrict__ ws, float* __restrict__ d_out)
{
    __shared__ float red[1024];
    __shared__ float msh;
    int t = threadIdx.x;
    float mx = -3.4e38f, sm = 0.f;
    for (int n = t; n < NCC; n += 1024) {
        float v = ws[WS_AVGT + n];
        mx = fmaxf(mx, v);
        sm += v;
    }
    red[t] = mx; __syncthreads();
    for (int st = 512; st > 0; st >>= 1) { if (t < st) red[t] = fmaxf(red[t], red[t + st]); __syncthreads(); }
    if (t == 0) msh = red[0];
    __syncthreads();
    float m = msh;
    red[t] = sm; __syncthreads();
    for (int st = 512; st > 0; st >>= 1) { if (t < st) red[t] += red[t + st]; __syncthreads(); }
    if (t == 0) d_out[64] = red[0] * (1.f / (float)NCC);
    __syncthreads();
    float se = 0.f;
    for (int n = t; n < NCC; n += 1024) se += __expf(ws[WS_AVGT + n] - m);
    red[t] = se; __syncthreads();
    for (int st = 512; st > 0; st >>= 1) { if (t < st) red[t] += red[t + st]; __syncthreads(); }
    if (t == 0) { ws[WS_STAT] = m; ws[WS_STAT + 1] = red[0]; }
}

// ---------------- softmax-weighted cell_out partial reduction ----------------
__global__ __launch_bounds__(256) void kred(float* __restrict__ ws)
{
    __shared__ float wexp[64];
    __shared__ float red[256];
    int blk = blockIdx.x, t = threadIdx.x;
    int n0 = blk * 64;
    float m = ws[WS_STAT];
    if (t < 64) wexp[t] = __expf(ws[WS_AVGT + n0 + t] - m);
    __syncthreads();
    int d = t & 63, q = t >> 6;
    float s = 0.f;
    for (int i = 0; i < 16; i++) {
        int c = q * 16 + i;
        s += wexp[c] * ws[WS_CO + (size_t)(n0 + c) * 64 + d];
    }
    red[t] = s; __syncthreads();
    if (t < 64)
        ws[WS_PART2 + blk * 64 + t] = red[t] + red[64 + t] + red[128 + t] + red[192 + t];
}

__global__ __launch_bounds__(256) void kpred(
    const float* __restrict__ headW, const float* __restrict__ headb,
    float* __restrict__ ws, float* __restrict__ d_out)
{
    __shared__ float red[256];
    __shared__ float comb[64];
    int t = threadIdx.x;
    int d = t & 63, q = t >> 6;
    float s = 0.f;
    for (int i = 0; i < 64; i++) s += ws[WS_PART2 + (q * 64 + i) * 64 + d];
    red[t] = s; __syncthreads();
    if (t < 64) comb[t] = (red[t] + red[64 + t] + red[128 + t] + red[192 + t]) / ws[WS_STAT + 1];
    __syncthreads();
    if (t < 64) {
        float p = headb[t];
        for (int d2 = 0; d2 < 64; d2++) p += comb[d2] * headW[t * 64 + d2];
        d_out[t] = p;
    }
}

extern "C" void kernel_launch(void* const* d_in, const int* in_sizes, int n_in,
                              void* d_out, int out_size, void* d_ws, size_t ws_size,
                              hipStream_t stream)
{
    const float* x       = (const float*)d_in[0];
    const float* noise   = (const float*)d_in[1];
    const float* amps    = (const float*)d_in[2];
    const float* hiddens = (const float*)d_in[3];
    const float* eaW1    = (const float*)d_in[4];
    const float* eaB1    = (const float*)d_in[5];
    const float* eaW2    = (const float*)d_in[6];
    const float* eaB2    = (const float*)d_in[7];
    const float* egW1    = (const float*)d_in[8];
    const float* egB1    = (const float*)d_in[9];
    const float* egW2    = (const float*)d_in[10];
    const float* egB2    = (const float*)d_in[11];
    const float* gWih    = (const float*)d_in[12];
    const float* gWhh    = (const float*)d_in[13];
    const float* gbih    = (const float*)d_in[14];
    const float* gbhh    = (const float*)d_in[15];
    const float* headW   = (const float*)d_in[16];
    const float* headb   = (const float*)d_in[17];
    const float* mixW    = (const float*)d_in[18];
    const float* mixb    = (const float*)d_in[19];
    const int*   step    = (const int*)d_in[20];

    float* out  = (float*)d_out;
    float* newh = out + 65;   // [pred(64), avg_t_mean(1), newh(8*16384*128)]
    float* ws   = (float*)d_ws;

    k0s<<<1, 256, 0, stream>>>(x, noise, amps, eaW1, eaB1, egW1, egB1,
                               eaB2, egB2, gbih, gbhh, gWih, ws);
    kfrag<<<120, 1024, 0, stream>>>(eaW1, egW1, eaW2, egW2, gWih, gWhh, ws);
    k1_cells<<<1024, 256, 0, stream>>>(hiddens, newh, ws);
    k2_fmean<<<64, 128, 0, stream>>>(ws);
    k2_glob<<<1, 1024, 0, stream>>>(ws);
    k4hm<<<1, 1024, 0, stream>>>(step, ws);
    k4mv<<<128, 256, 0, stream>>>(mixW, mixb, ws);
    k35_blend<<<2048, 256, 0, stream>>>(newh, ws, step);
    kstat<<<1, 1024, 0, stream>>>(ws, out);
    kred<<<256, 256, 0, stream>>>(ws);
    kpred<<<1, 256, 0, stream>>>(headW, headb, ws, out);
}